// Round 4
// baseline (181.098 us; speedup 1.0000x reference)
//
#include <hip/hip_runtime.h>
#include <hip/hip_bf16.h>

typedef __attribute__((ext_vector_type(4))) float f32x4;
typedef __attribute__((ext_vector_type(8))) short bf16x8;

#define NROWS 32768
#define DIM   2048
#define NEXP  64
#define NC    64          // K chunks of 32

__device__ __forceinline__ short f2bf(float f) {
    __hip_bfloat16 h = __float2bfloat16(f);   // RTNE
    short s;
    __builtin_memcpy(&s, &h, 2);
    return s;
}

// async global->LDS DMA, 16B per lane. lds base must be wave-uniform
// (HW adds lane*16 itself); global address is per-lane.
__device__ __forceinline__ void async16(const void* g, void* l) {
    __builtin_amdgcn_global_load_lds(
        (const __attribute__((address_space(1))) unsigned int*)g,
        (__attribute__((address_space(3))) unsigned int*)l, 16, 0, 0);
}

// ---------------- Kernel A: expert prep -------------------------------------
__global__ __launch_bounds__(256) void prep_experts(
    const float* __restrict__ ek,
    short* __restrict__ ekbf,
    short* __restrict__ ekT,
    float* __restrict__ enorm)
{
    const int e = blockIdx.x;      // expert 0..63
    const int t = threadIdx.x;     // 0..255
    const float* row = ek + e * DIM;
    float ss = 0.f;
#pragma unroll
    for (int i = 0; i < 2; ++i) {
        const int c4 = t + i * 256;              // float4 index 0..511
        const float4 v = ((const float4*)row)[c4];
        ss += v.x * v.x + v.y * v.y + v.z * v.z + v.w * v.w;
        short4 b;
        b.x = f2bf(v.x); b.y = f2bf(v.y); b.z = f2bf(v.z); b.w = f2bf(v.w);
        *(short4*)(ekbf + e * DIM + c4 * 4) = b;
        const int d = c4 * 4;
        ekT[(d + 0) * NEXP + e] = b.x;
        ekT[(d + 1) * NEXP + e] = b.y;
        ekT[(d + 2) * NEXP + e] = b.z;
        ekT[(d + 3) * NEXP + e] = b.w;
    }
#pragma unroll
    for (int s = 1; s < 64; s <<= 1) ss += __shfl_xor(ss, s);
    __shared__ float red[4];
    if ((t & 63) == 0) red[t >> 6] = ss;
    __syncthreads();
    if (t == 0) enorm[e] = sqrtf(red[0] + red[1] + red[2] + red[3]);
}

// ---------------- Main kernel ------------------------------------------------
// 64 rows/block, 4 waves. Phase 1: K chunks of 32 staged to LDS by
// global_load_lds, 4 buffers, 3 chunks (9 DMAs/wave) in flight, counted vmcnt.
// LDS read bank conflicts fixed by pre-swizzled GLOBAL source + swizzled read.

struct P3Buf { bf16x8 b0, b1; };

__device__ __forceinline__ void p3_load(P3Buf& b, const short* ekT,
                                        int w, int lr, int lg, int ntl) {
    const int d0 = w * 512 + ntl * 16;
    const short* bp = ekT + (size_t)(d0 + lr) * NEXP + lg * 8;
    b.b0 = *(const bf16x8*)bp;
    b.b1 = *(const bf16x8*)(bp + 32);
}

__global__ __launch_bounds__(256) void cosmoe_main(
    const float* __restrict__ z,
    const short* __restrict__ ekbf,   // [64][2048] bf16
    const short* __restrict__ ekT,    // [2048][64] bf16
    const float* __restrict__ enorm,  // [64] f32
    float* __restrict__ out_sim,      // [32768][64] f32
    float* __restrict__ out_wei)      // [32768][2048] f32
{
    const int tid = threadIdx.x;
    const int w   = tid >> 6;     // wave 0..3
    const int l   = tid & 63;
    const int lr  = l & 15;       // A-row / B-col / C-col within 16-tile
    const int lg  = l >> 4;       // k-group 0..3
    const int base_row = blockIdx.x * 64;

    __shared__ __align__(16) float zbuf[4][64][32];   // 32 KiB, row stride 128B
    __shared__ __align__(16) short ebuf[4][64][32];   // 16 KiB, row stride 64B
    __shared__ __align__(16) short Wl[4][16][72];     // 9 KiB

    // --- per-lane pre-swizzled global sources ------------------------------
    // z: instr covers 8 rows x 128B; 16B-unit s holds orig unit s^(row&7).
    const int zcolu = ((l & 7) ^ (l >> 3));           // 16B unit (4 floats)
    const float* zg0 = z + (size_t)(base_row + w * 16 + (l >> 3)) * DIM + zcolu * 4;
    const float* zg1 = z + (size_t)(base_row + w * 16 + 8 + (l >> 3)) * DIM + zcolu * 4;
    // ek: instr covers 16 rows x 64B; unit s holds orig unit s^(e&3).
    const int ecolu = ((l & 3) ^ ((l >> 2) & 3));     // 16B unit (8 bf16)
    const short* eg = ekbf + (size_t)(w * 16 + (l >> 2)) * DIM + ecolu * 8;

#define STAGE(c_) do { const int b_ = (c_) & 3;                     \
        async16(zg0 + (size_t)(c_) * 32, &zbuf[b_][w * 16][0]);     \
        async16(zg1 + (size_t)(c_) * 32, &zbuf[b_][w * 16 + 8][0]); \
        async16(eg  + (c_) * 32,         &ebuf[b_][w * 16][0]);     \
    } while (0)

    // ---- Phase 1: dots = z @ ek^T + f32 z sum-of-squares
    f32x4 acc[4];
#pragma unroll
    for (int nt = 0; nt < 4; ++nt) acc[nt] = f32x4{0.f, 0.f, 0.f, 0.f};
    float ss0 = 0.f, ss1 = 0.f;

    STAGE(0); STAGE(1); STAGE(2);                      // 9 DMAs/wave in flight

    for (int c = 0; c < NC; ++c) {
        if (c < NC - 2)       asm volatile("s_waitcnt vmcnt(6)" ::: "memory");
        else if (c == NC - 2) asm volatile("s_waitcnt vmcnt(3)" ::: "memory");
        else                  asm volatile("s_waitcnt vmcnt(0)" ::: "memory");
        __builtin_amdgcn_s_barrier();
        __builtin_amdgcn_sched_barrier(0);
        if (c < NC - 3) STAGE(c + 3);                  // issue early, hide HBM

        const int b = c & 3;
        const char* zrowp = (const char*)&zbuf[b][w * 16 + lr][0];
        const float4 a0 = *(const float4*)(zrowp + ((((lg * 2)    ) ^ (lr & 7)) << 4));
        const float4 a1 = *(const float4*)(zrowp + ((((lg * 2) + 1) ^ (lr & 7)) << 4));
        ss0 = fmaf(a0.x, a0.x, ss0); ss1 = fmaf(a0.y, a0.y, ss1);
        ss0 = fmaf(a0.z, a0.z, ss0); ss1 = fmaf(a0.w, a0.w, ss1);
        ss0 = fmaf(a1.x, a1.x, ss0); ss1 = fmaf(a1.y, a1.y, ss1);
        ss0 = fmaf(a1.z, a1.z, ss0); ss1 = fmaf(a1.w, a1.w, ss1);
        bf16x8 af;
        af[0] = f2bf(a0.x); af[1] = f2bf(a0.y); af[2] = f2bf(a0.z); af[3] = f2bf(a0.w);
        af[4] = f2bf(a1.x); af[5] = f2bf(a1.y); af[6] = f2bf(a1.z); af[7] = f2bf(a1.w);
        const int se = (lg ^ (lr & 3)) << 4;
#pragma unroll
        for (int nt = 0; nt < 4; ++nt) {
            const bf16x8 bf = *(const bf16x8*)((const char*)&ebuf[b][nt * 16 + lr][0] + se);
            acc[nt] = __builtin_amdgcn_mfma_f32_16x16x32_bf16(af, bf, acc[nt], 0, 0, 0);
        }
    }
#undef STAGE

    float ssq = ss0 + ss1;
    ssq += __shfl_xor(ssq, 16);
    ssq += __shfl_xor(ssq, 32);
    const float zn_mine = sqrtf(ssq);   // ||z[w*16+lr]||

    // ---- Phase 2: similarity + softmax over 64 experts.
    // C layout: lane holds D[lg*4+j][lr] per n-tile.
    float zn_j[4];
#pragma unroll
    for (int j = 0; j < 4; ++j) zn_j[j] = __shfl(zn_mine, lg * 4 + j);
    float en_nt[4];
#pragma unroll
    for (int nt = 0; nt < 4; ++nt) en_nt[nt] = enorm[nt * 16 + lr];

    float sim[4][4];   // [nt][j]
#pragma unroll
    for (int j = 0; j < 4; ++j)
#pragma unroll
        for (int nt = 0; nt < 4; ++nt)
            sim[nt][j] = acc[nt][j] / fmaxf(zn_j[j] * en_nt[nt], 1e-8f);

#pragma unroll
    for (int j = 0; j < 4; ++j) {
        const size_t ro = (size_t)(base_row + w * 16 + lg * 4 + j) * NEXP + lr;
#pragma unroll
        for (int nt = 0; nt < 4; ++nt) out_sim[ro + nt * 16] = sim[nt][j];
    }

    float wgt[4][4];
#pragma unroll
    for (int j = 0; j < 4; ++j) {
        float mx = fmaxf(fmaxf(sim[0][j], sim[1][j]), fmaxf(sim[2][j], sim[3][j]));
#pragma unroll
        for (int t = 1; t < 16; t <<= 1) mx = fmaxf(mx, __shfl_xor(mx, t));
        float sum = 0.f;
#pragma unroll
        for (int nt = 0; nt < 4; ++nt) { wgt[nt][j] = __expf(sim[nt][j] - mx); sum += wgt[nt][j]; }
#pragma unroll
        for (int t = 1; t < 16; t <<= 1) sum += __shfl_xor(sum, t);
        const float inv = 1.0f / sum;
#pragma unroll
        for (int nt = 0; nt < 4; ++nt) wgt[nt][j] *= inv;
    }

    // re-layout W: C-frag -> A-frag via padded LDS tile (stride 72 => 2-way max)
#pragma unroll
    for (int j = 0; j < 4; ++j)
#pragma unroll
        for (int nt = 0; nt < 4; ++nt)
            Wl[w][lg * 4 + j][nt * 16 + lr] = f2bf(wgt[nt][j]);
    __syncthreads();

    // ---- Phase 3: weighted = W[64x64] @ ek[64x2048]; wave w owns d-slice w*512
    bf16x8 afr[4][2];
#pragma unroll
    for (int mt = 0; mt < 4; ++mt)
#pragma unroll
        for (int ks = 0; ks < 2; ++ks)
            afr[mt][ks] = *(const bf16x8*)&Wl[mt][lr][ks * 32 + lg * 8];

    P3Buf PA, PB;
    p3_load(PA, ekT, w, lr, lg, 0);
    p3_load(PB, ekT, w, lr, lg, 1);

    for (int base = 0; base < 32; base += 2) {
        {
            const int d0 = w * 512 + base * 16;
            f32x4 oacc[4];
#pragma unroll
            for (int mt = 0; mt < 4; ++mt) {
                oacc[mt] = f32x4{0.f, 0.f, 0.f, 0.f};
                oacc[mt] = __builtin_amdgcn_mfma_f32_16x16x32_bf16(afr[mt][0], PA.b0, oacc[mt], 0, 0, 0);
                oacc[mt] = __builtin_amdgcn_mfma_f32_16x16x32_bf16(afr[mt][1], PA.b1, oacc[mt], 0, 0, 0);
            }
            if (base < 30) p3_load(PA, ekT, w, lr, lg, base + 2);
#pragma unroll
            for (int mt = 0; mt < 4; ++mt)
#pragma unroll
                for (int j = 0; j < 4; ++j)
                    out_wei[(size_t)(base_row + mt * 16 + lg * 4 + j) * DIM + d0 + lr] = oacc[mt][j];
        }
        {
            const int d0 = w * 512 + (base + 1) * 16;
            f32x4 oacc[4];
#pragma unroll
            for (int mt = 0; mt < 4; ++mt) {
                oacc[mt] = f32x4{0.f, 0.f, 0.f, 0.f};
                oacc[mt] = __builtin_amdgcn_mfma_f32_16x16x32_bf16(afr[mt][0], PB.b0, oacc[mt], 0, 0, 0);
                oacc[mt] = __builtin_amdgcn_mfma_f32_16x16x32_bf16(afr[mt][1], PB.b1, oacc[mt], 0, 0, 0);
            }
            if (base < 30) p3_load(PB, ekT, w, lr, lg, base + 3);
#pragma unroll
            for (int mt = 0; mt < 4; ++mt)
#pragma unroll
                for (int j = 0; j < 4; ++j)
                    out_wei[(size_t)(base_row + mt * 16 + lg * 4 + j) * DIM + d0 + lr] = oacc[mt][j];
        }
    }
}

// ---------------- launch -----------------------------------------------------
extern "C" void kernel_launch(void* const* d_in, const int* in_sizes, int n_in,
                              void* d_out, int out_size, void* d_ws, size_t ws_size,
                              hipStream_t stream) {
    const float* z  = (const float*)d_in[0];
    const float* ek = (const float*)d_in[1];
    float* out_sim = (float*)d_out;
    float* out_wei = out_sim + (size_t)NROWS * NEXP;

    short* ekbf  = (short*)d_ws;                 // 64*2048*2   = 256 KiB
    short* ekT   = ekbf + NEXP * DIM;            // 2048*64*2   = 256 KiB
    float* enorm = (float*)(ekT + DIM * NEXP);   // 64*4 bytes

    prep_experts<<<NEXP, 256, 0, stream>>>(ek, ekbf, ekT, enorm);
    cosmoe_main<<<NROWS / 64, 256, 0, stream>>>(z, ekbf, ekT, enorm, out_sim, out_wei);
}

// Round 5
// 171.278 us; speedup vs baseline: 1.0573x; 1.0573x over previous
//
#include <hip/hip_runtime.h>
#include <hip/hip_bf16.h>

typedef __attribute__((ext_vector_type(4))) float f32x4;
typedef __attribute__((ext_vector_type(8))) short bf16x8;

#define NROWS 32768
#define DIM   2048
#define NEXP  64

__device__ __forceinline__ short f2bf(float f) {
    __hip_bfloat16 h = __float2bfloat16(f);   // RTNE
    short s;
    __builtin_memcpy(&s, &h, 2);
    return s;
}

// ---------------- Kernel A: expert prep -------------------------------------
// ekbf [64][2048] bf16 row-major, ekT [2048][64] bf16, enorm[64] f32.
__global__ __launch_bounds__(256) void prep_experts(
    const float* __restrict__ ek,
    short* __restrict__ ekbf,
    short* __restrict__ ekT,
    float* __restrict__ enorm)
{
    const int e = blockIdx.x;
    const int t = threadIdx.x;
    const float* row = ek + e * DIM;
    float ss = 0.f;
#pragma unroll
    for (int i = 0; i < 2; ++i) {
        const int c4 = t + i * 256;
        const float4 v = ((const float4*)row)[c4];
        ss += v.x * v.x + v.y * v.y + v.z * v.z + v.w * v.w;
        short4 b;
        b.x = f2bf(v.x); b.y = f2bf(v.y); b.z = f2bf(v.z); b.w = f2bf(v.w);
        *(short4*)(ekbf + e * DIM + c4 * 4) = b;
        const int d = c4 * 4;
        ekT[(d + 0) * NEXP + e] = b.x;
        ekT[(d + 1) * NEXP + e] = b.y;
        ekT[(d + 2) * NEXP + e] = b.z;
        ekT[(d + 3) * NEXP + e] = b.w;
    }
#pragma unroll
    for (int s = 1; s < 64; s <<= 1) ss += __shfl_xor(ss, s);
    __shared__ float red[4];
    if ((t & 63) == 0) red[t >> 6] = ss;
    __syncthreads();
    if (t == 0) enorm[e] = sqrtf(red[0] + red[1] + red[2] + red[3]);
}

// ---------------- Kernel 1: similarity only (read-bound) --------------------
// 16 rows/block, 2048 blocks. 4 waves split K=2048 into quarters; split-K
// partials reduced once through LDS; wave 0 finishes sim and writes it.
__global__ __launch_bounds__(256) void sim_kernel(
    const float* __restrict__ z,
    const short* __restrict__ ekbf,   // [64][2048] bf16
    const float* __restrict__ enorm,  // [64]
    float* __restrict__ out_sim)      // [32768][64]
{
    const int tid = threadIdx.x;
    const int w   = tid >> 6;     // wave 0..3 = K-quarter
    const int l   = tid & 63;
    const int lr  = l & 15;
    const int lg  = l >> 4;
    const int base = blockIdx.x * 16;

    __shared__ float racc[4][64][20];   // stride 20 f32 = 80B (16B aligned, conflict-free)
    __shared__ float rssq[4][16];

    const float* zp = z    + (size_t)(base + lr) * DIM + w * 512 + lg * 8;
    const short* ep = ekbf + (size_t)lr * DIM          + w * 512 + lg * 8;

    f32x4 acc[4];
#pragma unroll
    for (int nt = 0; nt < 4; ++nt) acc[nt] = f32x4{0.f, 0.f, 0.f, 0.f};
    float s0 = 0.f, s1 = 0.f;

#pragma unroll 4
    for (int c = 0; c < 16; ++c) {
        const float4 a0 = *(const float4*)(zp + c * 32);
        const float4 a1 = *(const float4*)(zp + c * 32 + 4);
        s0 = fmaf(a0.x, a0.x, s0); s1 = fmaf(a0.y, a0.y, s1);
        s0 = fmaf(a0.z, a0.z, s0); s1 = fmaf(a0.w, a0.w, s1);
        s0 = fmaf(a1.x, a1.x, s0); s1 = fmaf(a1.y, a1.y, s1);
        s0 = fmaf(a1.z, a1.z, s0); s1 = fmaf(a1.w, a1.w, s1);
        bf16x8 af;
        af[0] = f2bf(a0.x); af[1] = f2bf(a0.y); af[2] = f2bf(a0.z); af[3] = f2bf(a0.w);
        af[4] = f2bf(a1.x); af[5] = f2bf(a1.y); af[6] = f2bf(a1.z); af[7] = f2bf(a1.w);
#pragma unroll
        for (int nt = 0; nt < 4; ++nt) {
            const bf16x8 bf = *(const bf16x8*)(ep + nt * 16 * DIM + c * 32);
            acc[nt] = __builtin_amdgcn_mfma_f32_16x16x32_bf16(af, bf, acc[nt], 0, 0, 0);
        }
    }
    float ssq = s0 + s1;
    ssq += __shfl_xor(ssq, 16);
    ssq += __shfl_xor(ssq, 32);

#pragma unroll
    for (int nt = 0; nt < 4; ++nt)
        *(f32x4*)&racc[w][l][nt * 4] = acc[nt];
    if (l < 16) rssq[w][l] = ssq;
    __syncthreads();

    if (w == 0) {
        f32x4 tot[4];
#pragma unroll
        for (int nt = 0; nt < 4; ++nt) {
            tot[nt] = *(const f32x4*)&racc[0][l][nt * 4];
#pragma unroll
            for (int w2 = 1; w2 < 4; ++w2)
                tot[nt] += *(const f32x4*)&racc[w2][l][nt * 4];
        }
        const float sq = rssq[0][lr] + rssq[1][lr] + rssq[2][lr] + rssq[3][lr];
        const float zn = sqrtf(sq);          // ||z[base+lr]||
        float zn_j[4];
#pragma unroll
        for (int j = 0; j < 4; ++j) zn_j[j] = __shfl(zn, lg * 4 + j);
        float en_nt[4];
#pragma unroll
        for (int nt = 0; nt < 4; ++nt) en_nt[nt] = enorm[nt * 16 + lr];
#pragma unroll
        for (int j = 0; j < 4; ++j) {
            const size_t ro = (size_t)(base + lg * 4 + j) * NEXP + lr;
#pragma unroll
            for (int nt = 0; nt < 4; ++nt)
                out_sim[ro + nt * 16] = tot[nt][j] / fmaxf(zn_j[j] * en_nt[nt], 1e-8f);
        }
    }
}

// ---------------- Kernel 2: softmax + weighted combine (write-bound) --------
// 32 rows x 1024 cols per block, grid (1024, 2). Reads sim, recomputes softmax,
// W @ ekT via MFMA, writes out_wei as full 256B row segments via LDS transpose.
__global__ __launch_bounds__(256) void moe_kernel(
    const float* __restrict__ sim,    // [32768][64]
    const short* __restrict__ ekT,    // [2048][64] bf16
    float* __restrict__ out_wei)      // [32768][2048]
{
    const int tid = threadIdx.x;
    const int w   = tid >> 6;
    const int l   = tid & 63;
    const int lr  = l & 15;
    const int lg  = l >> 4;
    const int base = blockIdx.x * 32;
    const int col0 = blockIdx.y * 1024 + w * 256;

    __shared__ __align__(16) short WL[32][64];      // [row][e] bf16, 16B-unit XOR swizzled
    __shared__ __align__(16) float tbuf[4][32][68]; // per-wave transpose buffer

    // --- softmax: thread t handles row t>>3, experts (t&7)*8 .. +8
    {
        const int r  = tid >> 3;
        const int cc = tid & 7;
        const float* sp = sim + (size_t)(base + r) * NEXP + cc * 8;
        const float4 v0 = *(const float4*)sp;
        const float4 v1 = *(const float4*)(sp + 4);
        float va[8] = {v0.x, v0.y, v0.z, v0.w, v1.x, v1.y, v1.z, v1.w};
        float m = va[0];
#pragma unroll
        for (int i = 1; i < 8; ++i) m = fmaxf(m, va[i]);
        m = fmaxf(m, __shfl_xor(m, 1));
        m = fmaxf(m, __shfl_xor(m, 2));
        m = fmaxf(m, __shfl_xor(m, 4));
        float sum = 0.f;
#pragma unroll
        for (int i = 0; i < 8; ++i) { va[i] = __expf(va[i] - m); sum += va[i]; }
        sum += __shfl_xor(sum, 1);
        sum += __shfl_xor(sum, 2);
        sum += __shfl_xor(sum, 4);
        const float inv = 1.0f / sum;
        bf16x8 wv;
#pragma unroll
        for (int i = 0; i < 8; ++i) wv[i] = f2bf(va[i] * inv);
        // physical 16B unit = logical unit (cc) XOR (row&7)
        *(bf16x8*)&WL[r][(cc ^ (r & 7)) * 8] = wv;
    }
    __syncthreads();

    // --- A-fragments: afr[mt][ks] = W[mt*16+lr][ks*32 + lg*8 ..+8]
    bf16x8 afr[2][2];
#pragma unroll
    for (int mt = 0; mt < 2; ++mt)
#pragma unroll
        for (int ks = 0; ks < 2; ++ks) {
            const int row = mt * 16 + lr;
            const int u   = (ks * 4 + lg) ^ (row & 7);
            afr[mt][ks] = *(const bf16x8*)&WL[row][u * 8];
        }

    // --- main: 4 groups of 64 cols each (wave slice = 256 cols)
#pragma unroll 1
    for (int g = 0; g < 4; ++g) {
        f32x4 oacc[4][2];   // [nt2][mt]
#pragma unroll
        for (int nt2 = 0; nt2 < 4; ++nt2) {
            const int d0 = col0 + g * 64 + nt2 * 16;
            const short* bp = ekT + (size_t)(d0 + lr) * NEXP + lg * 8;
            const bf16x8 b0 = *(const bf16x8*)bp;
            const bf16x8 b1 = *(const bf16x8*)(bp + 32);
#pragma unroll
            for (int mt = 0; mt < 2; ++mt) {
                f32x4 o = f32x4{0.f, 0.f, 0.f, 0.f};
                o = __builtin_amdgcn_mfma_f32_16x16x32_bf16(afr[mt][0], b0, o, 0, 0, 0);
                o = __builtin_amdgcn_mfma_f32_16x16x32_bf16(afr[mt][1], b1, o, 0, 0, 0);
                oacc[nt2][mt] = o;
            }
        }
        // transpose fragments -> row-major tile (per-wave buffer, no block sync)
#pragma unroll
        for (int nt2 = 0; nt2 < 4; ++nt2)
#pragma unroll
            for (int mt = 0; mt < 2; ++mt)
#pragma unroll
                for (int j = 0; j < 4; ++j)
                    tbuf[w][mt * 16 + lg * 4 + j][nt2 * 16 + lr] = oacc[nt2][mt][j];
        // write 32 rows x 64 cols as float4: 4 full rows (256B each) per instr
#pragma unroll
        for (int i = 0; i < 8; ++i) {
            const int row  = (l >> 4) + i * 4;
            const int unit = l & 15;
            const float4 t = *(const float4*)&tbuf[w][row][unit * 4];
            *(float4*)&out_wei[(size_t)(base + row) * DIM + col0 + g * 64 + unit * 4] = t;
        }
    }
}

// ---------------- launch -----------------------------------------------------
extern "C" void kernel_launch(void* const* d_in, const int* in_sizes, int n_in,
                              void* d_out, int out_size, void* d_ws, size_t ws_size,
                              hipStream_t stream) {
    const float* z  = (const float*)d_in[0];
    const float* ek = (const float*)d_in[1];
    float* out_sim = (float*)d_out;
    float* out_wei = out_sim + (size_t)NROWS * NEXP;

    short* ekbf  = (short*)d_ws;                 // 256 KiB
    short* ekT   = ekbf + NEXP * DIM;            // 256 KiB
    float* enorm = (float*)(ekT + DIM * NEXP);   // 256 B

    prep_experts<<<NEXP, 256, 0, stream>>>(ek, ekbf, ekT, enorm);
    sim_kernel<<<NROWS / 16, 256, 0, stream>>>(z, ekbf, enorm, out_sim);
    moe_kernel<<<dim3(NROWS / 32, 2), 256, 0, stream>>>(out_sim, ekT, out_wei);
}

// Round 6
// 147.477 us; speedup vs baseline: 1.2280x; 1.1614x over previous
//
#include <hip/hip_runtime.h>
#include <hip/hip_bf16.h>

typedef __attribute__((ext_vector_type(4))) float f32x4;
typedef __attribute__((ext_vector_type(8))) short bf16x8;

#define NROWS 32768
#define DIM   2048
#define NEXP  64
#define BKF   128              // K-chunk (f32 elements)
#define NCH   (DIM / BKF)      // 16 chunks

__device__ __forceinline__ short f2bf(float f) {
    __hip_bfloat16 h = __float2bfloat16(f);   // RTNE
    short s;
    __builtin_memcpy(&s, &h, 2);
    return s;
}

// async global->LDS DMA, 16B per lane; LDS dest wave-uniform (HW adds lane*16).
__device__ __forceinline__ void async16(const void* g, void* l) {
    __builtin_amdgcn_global_load_lds(
        (const __attribute__((address_space(1))) unsigned int*)g,
        (__attribute__((address_space(3))) unsigned int*)l, 16, 0, 0);
}

// ---------------- Kernel A: expert prep -------------------------------------
__global__ __launch_bounds__(256) void prep_experts(
    const float* __restrict__ ek,
    short* __restrict__ ekbf,
    short* __restrict__ ekT,
    float* __restrict__ enorm)
{
    const int e = blockIdx.x;
    const int t = threadIdx.x;
    const float* row = ek + e * DIM;
    float ss = 0.f;
#pragma unroll
    for (int i = 0; i < 2; ++i) {
        const int c4 = t + i * 256;
        const float4 v = ((const float4*)row)[c4];
        ss += v.x * v.x + v.y * v.y + v.z * v.z + v.w * v.w;
        short4 b;
        b.x = f2bf(v.x); b.y = f2bf(v.y); b.z = f2bf(v.z); b.w = f2bf(v.w);
        *(short4*)(ekbf + e * DIM + c4 * 4) = b;
        const int d = c4 * 4;
        ekT[(d + 0) * NEXP + e] = b.x;
        ekT[(d + 1) * NEXP + e] = b.y;
        ekT[(d + 2) * NEXP + e] = b.z;
        ekT[(d + 3) * NEXP + e] = b.w;
    }
#pragma unroll
    for (int s = 1; s < 64; s <<= 1) ss += __shfl_xor(ss, s);
    __shared__ float red[4];
    if ((t & 63) == 0) red[t >> 6] = ss;
    __syncthreads();
    if (t == 0) enorm[e] = sqrtf(red[0] + red[1] + red[2] + red[3]);
}

// ---------------- Kernel 1: similarity (read-bound, streaming-shaped) -------
// 32 rows/block, 1024 blocks, 4 waves. z and ek staged to LDS by
// global_load_lds in CONTIGUOUS 1KiB spans (2 z-rows x 512B / 4 ek-rows x
// 256B per instruction), double-buffered, counted vmcnt(8). Global source is
// XOR-pre-swizzled so LDS fragment reads hit the b128 floor (8 lanes/quad).
// Wave w computes experts w*16..w*16+15 for all 32 rows (2 m-tiles).
__global__ __launch_bounds__(256) void sim_kernel(
    const float* __restrict__ z,
    const short* __restrict__ ekbf,   // [64][2048] bf16
    const float* __restrict__ enorm,  // [64]
    float* __restrict__ out_sim)      // [32768][64]
{
    const int tid = threadIdx.x;
    const int w   = tid >> 6;
    const int l   = tid & 63;
    const int lr  = l & 15;
    const int lg  = l >> 4;
    const int base = blockIdx.x * 32;

    __shared__ __align__(16) float zbuf[2][32][BKF];   // 2 x 16 KiB
    __shared__ __align__(16) short ebuf[2][64][BKF];   // 2 x 16 KiB

    f32x4 acc[2];
    acc[0] = f32x4{0.f, 0.f, 0.f, 0.f};
    acc[1] = f32x4{0.f, 0.f, 0.f, 0.f};
    float sqa[2] = {0.f, 0.f}, sqb[2] = {0.f, 0.f};

    auto STAGE = [&](int c_) {
        const int b_ = c_ & 1;
#pragma unroll
        for (int i = 0; i < 4; ++i) {               // z rows w*8 .. w*8+7
            const int r0 = w * 8 + i * 2;
            const int zr = r0 + (l >> 5);           // 2 rows / instr (512B each)
            async16(z + (size_t)(base + zr) * DIM + c_ * BKF
                      + (((l & 31) ^ (zr & 7)) << 2),
                    &zbuf[b_][r0][0]);
        }
#pragma unroll
        for (int i = 0; i < 4; ++i) {               // ek rows w*16 .. w*16+15
            const int r0 = w * 16 + i * 4;
            const int er = r0 + (l >> 4);           // 4 rows / instr (256B each)
            async16(ekbf + (size_t)er * DIM + c_ * BKF
                         + (((l & 15) ^ (er & 7)) << 3),
                    &ebuf[b_][r0][0]);
        }
    };

    STAGE(0); STAGE(1);                              // 16 DMAs/wave in flight

    for (int c = 0; c < NCH; ++c) {
        if (c < NCH - 1) asm volatile("s_waitcnt vmcnt(8)" ::: "memory");
        else             asm volatile("s_waitcnt vmcnt(0)" ::: "memory");
        __builtin_amdgcn_s_barrier();
        __builtin_amdgcn_sched_barrier(0);
        const int b = c & 1;

#pragma unroll
        for (int kk = 0; kk < BKF / 32; ++kk) {
            // B-frag: expert row w*16+lr, k kk*32+lg*8 (swizzled unit)
            const int eu = ((kk * 4 + lg) ^ (lr & 7)) << 4;
            const bf16x8 bf =
                *(const bf16x8*)((const char*)&ebuf[b][w * 16 + lr][0] + eu);
#pragma unroll
            for (int mt = 0; mt < 2; ++mt) {
                const int zr = mt * 16 + lr;
                const int u0 = ((kk * 8 + lg * 2)     ^ (lr & 7)) << 4;
                const int u1 = ((kk * 8 + lg * 2 + 1) ^ (lr & 7)) << 4;
                const float4 a0 = *(const float4*)((const char*)&zbuf[b][zr][0] + u0);
                const float4 a1 = *(const float4*)((const char*)&zbuf[b][zr][0] + u1);
                sqa[mt] = fmaf(a0.x, a0.x, sqa[mt]); sqb[mt] = fmaf(a0.y, a0.y, sqb[mt]);
                sqa[mt] = fmaf(a0.z, a0.z, sqa[mt]); sqb[mt] = fmaf(a0.w, a0.w, sqb[mt]);
                sqa[mt] = fmaf(a1.x, a1.x, sqa[mt]); sqb[mt] = fmaf(a1.y, a1.y, sqb[mt]);
                sqa[mt] = fmaf(a1.z, a1.z, sqa[mt]); sqb[mt] = fmaf(a1.w, a1.w, sqb[mt]);
                bf16x8 af;
                af[0] = f2bf(a0.x); af[1] = f2bf(a0.y); af[2] = f2bf(a0.z); af[3] = f2bf(a0.w);
                af[4] = f2bf(a1.x); af[5] = f2bf(a1.y); af[6] = f2bf(a1.z); af[7] = f2bf(a1.w);
                acc[mt] = __builtin_amdgcn_mfma_f32_16x16x32_bf16(af, bf, acc[mt], 0, 0, 0);
            }
        }
        __builtin_amdgcn_s_barrier();                // all waves done reading buf
        if (c + 2 < NCH) STAGE(c + 2);
    }

    // norms + similarity write. C layout: lane holds D[lg*4+j][lr].
    const float en = enorm[w * 16 + lr];
#pragma unroll
    for (int mt = 0; mt < 2; ++mt) {
        float ss = sqa[mt] + sqb[mt];
        ss += __shfl_xor(ss, 16);
        ss += __shfl_xor(ss, 32);
        const float zn = sqrtf(ss);                  // ||z[base+mt*16+lr]||
#pragma unroll
        for (int j = 0; j < 4; ++j) {
            const float znj = __shfl(zn, lg * 4 + j);
            out_sim[(size_t)(base + mt * 16 + lg * 4 + j) * NEXP + w * 16 + lr]
                = acc[mt][j] / fmaxf(znj * en, 1e-8f);
        }
    }
}

// ---------------- Kernel 2: softmax + weighted combine (write-bound) --------
__global__ __launch_bounds__(256) void moe_kernel(
    const float* __restrict__ sim,    // [32768][64]
    const short* __restrict__ ekT,    // [2048][64] bf16
    float* __restrict__ out_wei)      // [32768][2048]
{
    const int tid = threadIdx.x;
    const int w   = tid >> 6;
    const int l   = tid & 63;
    const int lr  = l & 15;
    const int lg  = l >> 4;
    const int base = blockIdx.x * 32;
    const int col0 = blockIdx.y * 1024 + w * 256;

    __shared__ __align__(16) short WL[32][64];      // [row][e], 16B-unit XOR swizzled
    __shared__ __align__(16) float tbuf[4][32][68]; // per-wave transpose buffer

    {   // softmax: thread t -> row t>>3, experts (t&7)*8..+8
        const int r  = tid >> 3;
        const int cc = tid & 7;
        const float* sp = sim + (size_t)(base + r) * NEXP + cc * 8;
        const float4 v0 = *(const float4*)sp;
        const float4 v1 = *(const float4*)(sp + 4);
        float va[8] = {v0.x, v0.y, v0.z, v0.w, v1.x, v1.y, v1.z, v1.w};
        float m = va[0];
#pragma unroll
        for (int i = 1; i < 8; ++i) m = fmaxf(m, va[i]);
        m = fmaxf(m, __shfl_xor(m, 1));
        m = fmaxf(m, __shfl_xor(m, 2));
        m = fmaxf(m, __shfl_xor(m, 4));
        float sum = 0.f;
#pragma unroll
        for (int i = 0; i < 8; ++i) { va[i] = __expf(va[i] - m); sum += va[i]; }
        sum += __shfl_xor(sum, 1);
        sum += __shfl_xor(sum, 2);
        sum += __shfl_xor(sum, 4);
        const float inv = 1.0f / sum;
        bf16x8 wv;
#pragma unroll
        for (int i = 0; i < 8; ++i) wv[i] = f2bf(va[i] * inv);
        *(bf16x8*)&WL[r][(cc ^ (r & 7)) * 8] = wv;
    }
    __syncthreads();

    bf16x8 afr[2][2];
#pragma unroll
    for (int mt = 0; mt < 2; ++mt)
#pragma unroll
        for (int ks = 0; ks < 2; ++ks) {
            const int row = mt * 16 + lr;
            const int u   = (ks * 4 + lg) ^ (row & 7);
            afr[mt][ks] = *(const bf16x8*)&WL[row][u * 8];
        }

#pragma unroll 1
    for (int g = 0; g < 4; ++g) {
        f32x4 oacc[4][2];
#pragma unroll
        for (int nt2 = 0; nt2 < 4; ++nt2) {
            const int d0 = col0 + g * 64 + nt2 * 16;
            const short* bp = ekT + (size_t)(d0 + lr) * NEXP + lg * 8;
            const bf16x8 b0 = *(const bf16x8*)bp;
            const bf16x8 b1 = *(const bf16x8*)(bp + 32);
#pragma unroll
            for (int mt = 0; mt < 2; ++mt) {
                f32x4 o = f32x4{0.f, 0.f, 0.f, 0.f};
                o = __builtin_amdgcn_mfma_f32_16x16x32_bf16(afr[mt][0], b0, o, 0, 0, 0);
                o = __builtin_amdgcn_mfma_f32_16x16x32_bf16(afr[mt][1], b1, o, 0, 0, 0);
                oacc[nt2][mt] = o;
            }
        }
#pragma unroll
        for (int nt2 = 0; nt2 < 4; ++nt2)
#pragma unroll
            for (int mt = 0; mt < 2; ++mt)
#pragma unroll
                for (int j = 0; j < 4; ++j)
                    tbuf[w][mt * 16 + lg * 4 + j][nt2 * 16 + lr] = oacc[nt2][mt][j];
#pragma unroll
        for (int i = 0; i < 8; ++i) {
            const int row  = (l >> 4) + i * 4;
            const int unit = l & 15;
            const float4 t = *(const float4*)&tbuf[w][row][unit * 4];
            *(float4*)&out_wei[(size_t)(base + row) * DIM + col0 + g * 64 + unit * 4] = t;
        }
    }
}

// ---------------- launch -----------------------------------------------------
extern "C" void kernel_launch(void* const* d_in, const int* in_sizes, int n_in,
                              void* d_out, int out_size, void* d_ws, size_t ws_size,
                              hipStream_t stream) {
    const float* z  = (const float*)d_in[0];
    const float* ek = (const float*)d_in[1];
    float* out_sim = (float*)d_out;
    float* out_wei = out_sim + (size_t)NROWS * NEXP;

    short* ekbf  = (short*)d_ws;                 // 256 KiB
    short* ekT   = ekbf + NEXP * DIM;            // 256 KiB
    float* enorm = (float*)(ekT + DIM * NEXP);   // 256 B

    prep_experts<<<NEXP, 256, 0, stream>>>(ek, ekbf, ekT, enorm);
    sim_kernel<<<NROWS / 32, 256, 0, stream>>>(z, ekbf, enorm, out_sim);
    moe_kernel<<<dim3(NROWS / 32, 2), 256, 0, stream>>>(out_sim, ekT, out_wei);
}